// Round 1
// baseline (472.816 us; speedup 1.0000x reference)
//
#include <hip/hip_runtime.h>
#include <math.h>

// N=4, S=2048, D=1024, fp32 in/out.
// Pipeline (ALL GEMMs are GLL-staged f16-plane MFMA; conversion happens once in a pre-pass):
//   split   : q,k -> hi/lo planes ; v,WV -> hi ; WQ,WK -> hi/lo
//   wq = q@WQt, wk = k@WKt : triple-product (hh+hl+lh) GLL GEMM, split-plane out (128^2 template)
//   wvT = (v@WVt)^T        : single-product GLL GEMM, f16 hi transposed out [n][o][s]
//   Sc = wq@wkt            : NEW 256^2 deep-pipelined triple GLL GEMM, f32 out + fused column stats
//   combine                : fold 8 q-chunk partials -> m[k], r[k]=1/sum
//   pmat                   : P_hi = (f16) exp(Sc - m[k]) * r[k]
//   out = (P @ wvT^T)/1024 : single-product GLL GEMM, f32 out
// Workspace (f16 units, NSD = 8388608, DD = 1048576; peak < 10*NSD budget):
//   [0,1)N      q_hi   ; later wvT_hi (q dead after q-proj)
//   [1,2)N      q_lo   ; later Sc f32 spans [1,5)N (q_lo/k/v dead by then)
//   [2,4)N      k_hi|k_lo
//   [4,5)N      v_hi
//   [5N,5N+5DD) WQ_hi|WQ_lo|WK_hi|WK_lo|WV_hi
//   [5N+5DD, 9N+5DD) wq_hi|wq_lo|wk_hi|wk_lo ; later P_hi aliases wq_hi..(2N)
//   [9N+5DD, ..) stats (pm|ps|statM|statR, ~0.6 MB)

typedef _Float16 f16;
typedef _Float16 f16x8 __attribute__((ext_vector_type(8)));
typedef _Float16 f16x4 __attribute__((ext_vector_type(4)));
typedef float f32x4 __attribute__((ext_vector_type(4)));

enum StageMode { SM_PLANES2, SM_PLANES1 };
enum EpiMode   { EPI_F32, EPI_SPLIT, EPI_F16T };

#define GLL_PITCH 32   // f16 units/row; unpadded, XOR-swizzled 16B chunks

// async global->LDS, 16B per lane; LDS dest = wave-uniform base + lane*16
__device__ __forceinline__ void gll16(const f16* g, f16* l) {
    __builtin_amdgcn_global_load_lds(
        (const __attribute__((address_space(1))) void*)g,
        (__attribute__((address_space(3))) void*)l, 16, 0, 0);
}

// Stage one 128x32 f16 plane via GLL with XOR chunk swizzle (4-wave version, old template).
// Physical 16B slot t holds data (row = t>>2, chunk = (t&3) ^ ((row>>1)&3)).
__device__ __forceinline__ void stage_gll_plane(const f16* __restrict__ gplane,
                                                f16* __restrict__ lds,
                                                long rowBase, int ld, int k0,
                                                int wave, int lane)
{
#pragma unroll
    for (int i = 0; i < 2; i++) {
        int slotBase = (wave * 2 + i) * 64;
        int t = slotBase + lane;
        int r = t >> 2;
        int c = (t & 3) ^ ((r >> 1) & 3);
        const f16* g = gplane + (rowBase + r) * (long)ld + k0 + c * 8;
        gll16(g, lds + (long)slotBase * 8);   // wave-uniform LDS base
    }
}

__device__ __forceinline__ int frag_off_gll(int row, int g) {
    return row * GLL_PITCH + ((g ^ ((row >> 1) & 3)) << 3);
}

// ---------------------------------------------------------------------------
// Old 128x128 template (projections + final GEMM).
// C = A * B^T. A: [M,K], B: [Nc,K] row-major f16 planes (per batch plane).
// Tile 128x128, BK=32, 256 threads = 4 waves, each wave 64x64 (4x4 of 16x16x32).
template<StageMode SA, StageMode SB, EpiMode EP, int GROUPM, bool STATS>
__global__ __launch_bounds__(256, 4)
void mfma_gemm(const f16* __restrict__ Ahi, const f16* __restrict__ Alo,
               const f16* __restrict__ Bhi, const f16* __restrict__ Blo,
               float* __restrict__ pmOut, float* __restrict__ psOut,
               void* __restrict__ C0, void* __restrict__ C1,
               int M, int Nc, int K, int lda, int ldb, int ldc,
               long batchA, long batchB, long batchC,
               float epiScale, int tsShift)
{
    constexpr bool TRIPLE = (SA == SM_PLANES2);
    constexpr int PLANE_SZ = 128 * GLL_PITCH;

    int bx, by;
    if constexpr (GROUPM > 0) {
        int gx = gridDim.x;
        int lin = blockIdx.y * gx + blockIdx.x;
        int nig = GROUPM * gx;
        int gid = lin / nig;
        int rem = lin - gid * nig;
        by = gid * GROUPM + (rem % GROUPM);
        bx = rem / GROUPM;
    } else {
        bx = blockIdx.x;
        by = blockIdx.y;
    }
    const int n0 = bx * 128;
    const int m0 = by * 128;
    const long z = blockIdx.z;

    const long aOfs = z * batchA, bOfs = z * batchB, cOfs = z * batchC;

    __shared__ __align__(16) f16 As_hi[PLANE_SZ];
    __shared__ __align__(16) f16 Bs_hi[PLANE_SZ];
    __shared__ __align__(16) f16 As_lo[TRIPLE ? PLANE_SZ : 8];
    __shared__ __align__(16) f16 Bs_lo[TRIPLE ? PLANE_SZ : 8];

    const int tid  = threadIdx.x;
    const int lane = tid & 63;
    const int wave = tid >> 6;
    const int wr = (wave >> 1) * 64;
    const int wc = (wave & 1) * 64;
    const int fm = lane & 15;
    const int fg = lane >> 4;        // k-chunk index 0..3

    f32x4 acc[4][4];
#pragma unroll
    for (int i = 0; i < 4; i++)
#pragma unroll
        for (int j = 0; j < 4; j++) acc[i][j] = (f32x4){0.f, 0.f, 0.f, 0.f};

    int roA[4], roB[4];
#pragma unroll
    for (int i = 0; i < 4; i++) {
        roA[i] = frag_off_gll(wr + i * 16 + fm, fg);
        roB[i] = frag_off_gll(wc + i * 16 + fm, fg);
    }

    for (int k0 = 0; k0 < K; k0 += 32) {
        stage_gll_plane(Ahi + aOfs, As_hi, m0, lda, k0, wave, lane);
        stage_gll_plane(Bhi + bOfs, Bs_hi, n0, ldb, k0, wave, lane);
        if constexpr (TRIPLE) {
            stage_gll_plane(Alo + aOfs, As_lo, m0, lda, k0, wave, lane);
            stage_gll_plane(Blo + bOfs, Bs_lo, n0, ldb, k0, wave, lane);
        }
        __syncthreads();

        f16x8 ah[4], bh[4], al[4], bl[4];
#pragma unroll
        for (int i = 0; i < 4; i++) {
            ah[i] = *(const f16x8*)&As_hi[roA[i]];
            bh[i] = *(const f16x8*)&Bs_hi[roB[i]];
            if constexpr (TRIPLE) {
                al[i] = *(const f16x8*)&As_lo[roA[i]];
                bl[i] = *(const f16x8*)&Bs_lo[roB[i]];
            }
        }
#pragma unroll
        for (int i = 0; i < 4; i++) {
#pragma unroll
            for (int j = 0; j < 4; j++) {
                acc[i][j] = __builtin_amdgcn_mfma_f32_16x16x32_f16(ah[i], bh[j], acc[i][j], 0, 0, 0);
                if constexpr (TRIPLE) {
                    acc[i][j] = __builtin_amdgcn_mfma_f32_16x16x32_f16(ah[i], bl[j], acc[i][j], 0, 0, 0);
                    acc[i][j] = __builtin_amdgcn_mfma_f32_16x16x32_f16(al[i], bh[j], acc[i][j], 0, 0, 0);
                }
            }
        }
        __syncthreads();
    }

    // Epilogue. C/D frag: col = lane&15, row = (lane>>4)*4 + reg  [m89-verified]
    const int cr = fg * 4;
    const int cn = fm;
#pragma unroll
    for (int i = 0; i < 4; i++) {
#pragma unroll
        for (int j = 0; j < 4; j++) {
#pragma unroll
            for (int r = 0; r < 4; r++) {
                long mg = m0 + wr + i * 16 + cr + r;
                long ng = n0 + wc + j * 16 + cn;
                float val = acc[i][j][r] * epiScale;
                if constexpr (EP == EPI_F32) {
                    ((float*)C0)[cOfs + mg * ldc + ng] = val;
                } else if constexpr (EP == EPI_SPLIT) {
                    f16 h = (f16)val;
                    ((f16*)C0)[cOfs + mg * ldc + ng] = h;
                    ((f16*)C1)[cOfs + mg * ldc + ng] = (f16)(val - (float)h);
                } else { // EPI_F16T: batch folded in M; write [nb][n][s], hi only
                    long TS = 1L << tsShift;
                    long nb = mg >> tsShift;
                    long s  = mg & (TS - 1);
                    long addr = nb * ((long)Nc << tsShift) + ng * TS + s;
                    ((f16*)C0)[addr] = (f16)val;
                }
            }
        }
    }

    // (STATS path retained for template completeness; scores now use scores_gemm.)
    if constexpr (STATS) {
        __shared__ float stM[2][128];
        __shared__ float stS[2][128];
#pragma unroll
        for (int j = 0; j < 4; j++) {
            float mj = -3.402823466e38f;
#pragma unroll
            for (int i = 0; i < 4; i++)
#pragma unroll
                for (int r = 0; r < 4; r++) mj = fmaxf(mj, acc[i][j][r]);
            float sj = 0.f;
#pragma unroll
            for (int i = 0; i < 4; i++)
#pragma unroll
                for (int r = 0; r < 4; r++) sj += __expf(acc[i][j][r] - mj);
#pragma unroll
            for (int mask = 16; mask <= 32; mask <<= 1) {
                float mo = __shfl_xor(mj, mask, 64);
                float so = __shfl_xor(sj, mask, 64);
                float mn = fmaxf(mj, mo);
                sj = sj * __expf(mj - mn) + so * __expf(mo - mn);
                mj = mn;
            }
            if (fg == 0) {
                stM[wave >> 1][wc + j * 16 + cn] = mj;
                stS[wave >> 1][wc + j * 16 + cn] = sj;
            }
        }
        __syncthreads();
        if (tid < 128) {
            float ma = stM[0][tid], mb = stM[1][tid];
            float Mc = fmaxf(ma, mb);
            float Sv = stS[0][tid] * __expf(ma - Mc) + stS[1][tid] * __expf(mb - Mc);
            long o = ((long)z * (M >> 7) + by) * (long)Nc + (long)bx * 128 + tid;
            pmOut[o] = Mc;
            psOut[o] = Sv;
        }
    }
}

// ---------------------------------------------------------------------------
// NEW: deep-pipelined 256x256 scores GEMM. C = A @ B^T per batch, triple-product
// f16 split planes, BK=32, 512 threads = 8 waves (2M x 4N), per-wave 128x64.
// Schedule (T3/T4/T5 adaptation):
//   - double-buffered LDS (4 planes x 2 x 16KB = 128KB), ONE barrier per K-tile;
//   - staging for tile t+1 is issued AFTER the barrier and consumed next
//     iteration, so the barrier's implicit vmcnt(0) only drains loads that had
//     a full tile of MFMA (~960 cy) to land — loads span the compute phase;
//   - B frags hoisted once/tile, A per 128-row half (24 ds_read/tile);
//   - s_setprio(1) around each 48-MFMA cluster (waves free-run between barriers).
// Grid (S/256, S/256, N) = 256 blocks = 1 block/CU, no tail.
// Fused column-softmax partials (8 q-chunks of 256 rows).
__global__ __launch_bounds__(512, 2)
void scores_gemm(const f16* __restrict__ Ahi, const f16* __restrict__ Alo,
                 const f16* __restrict__ Bhi, const f16* __restrict__ Blo,
                 float* __restrict__ pmOut, float* __restrict__ psOut,
                 float* __restrict__ C,
                 int M, int Nc, int K, int lda, int ldb, int ldc,
                 long batchA, long batchB, long batchC)
{
    constexpr int PLANE = 256 * GLL_PITCH;   // 8192 f16 = 16 KB

    __shared__ __align__(16) f16 As_hi[2][PLANE];
    __shared__ __align__(16) f16 As_lo[2][PLANE];
    __shared__ __align__(16) f16 Bs_hi[2][PLANE];
    __shared__ __align__(16) f16 Bs_lo[2][PLANE];

    const int tid  = threadIdx.x;
    const int lane = tid & 63;
    const int wave = tid >> 6;
    const int rw   = wave >> 2;      // 0..1 : row half (128 rows)
    const int cw   = wave & 3;       // 0..3 : col quarter (64 cols)
    const int wrM  = rw * 128;
    const int wrN  = cw * 64;
    const int fm   = lane & 15;
    const int fg   = lane >> 4;      // k-chunk index 0..3

    const int n0 = blockIdx.x * 256;
    const int m0 = blockIdx.y * 256;
    const long z = blockIdx.z;
    const long aOfs = z * batchA, bOfs = z * batchB, cOfs = z * batchC;

    // staging: 1024 16B slots per 256x32 plane; this thread owns two.
    // slot t holds (row = t>>2, chunk = (t&3) ^ ((row>>1)&3)) — same swizzle as
    // the 128^2 template (measured conflict-free), generalized to 8 waves.
    int slotBase[2], srcA[2], srcB[2];
#pragma unroll
    for (int i = 0; i < 2; i++) {
        int sb = (wave * 2 + i) * 64;        // wave-uniform slot base
        int t  = sb + lane;
        int r  = t >> 2;
        int c  = (t & 3) ^ ((r >> 1) & 3);
        slotBase[i] = sb * 8;                // f16 units
        srcA[i] = (m0 + r) * lda + c * 8;
        srcB[i] = (n0 + r) * ldb + c * 8;
    }

#define SC_STAGE(buf, k0) do {                                              \
    _Pragma("unroll")                                                        \
    for (int s_ = 0; s_ < 2; s_++) {                                         \
        gll16(Ahi + aOfs + srcA[s_] + (k0), &As_hi[buf][slotBase[s_]]);      \
        gll16(Alo + aOfs + srcA[s_] + (k0), &As_lo[buf][slotBase[s_]]);      \
        gll16(Bhi + bOfs + srcB[s_] + (k0), &Bs_hi[buf][slotBase[s_]]);      \
        gll16(Blo + bOfs + srcB[s_] + (k0), &Bs_lo[buf][slotBase[s_]]);      \
    } } while (0)

    f32x4 acc[8][4];
#pragma unroll
    for (int i = 0; i < 8; i++)
#pragma unroll
        for (int j = 0; j < 4; j++) acc[i][j] = (f32x4){0.f, 0.f, 0.f, 0.f};

    int roA[8], roB[4];
#pragma unroll
    for (int i = 0; i < 8; i++) roA[i] = frag_off_gll(wrM + i * 16 + fm, fg);
#pragma unroll
    for (int j = 0; j < 4; j++) roB[j] = frag_off_gll(wrN + j * 16 + fm, fg);

    const int NT = K >> 5;     // 32 K-tiles
    SC_STAGE(0, 0);

    for (int t = 0; t < NT; t++) {
        const int cur = t & 1;
        // implicit vmcnt(0)+lgkmcnt(0): tile t's staging (issued last iter,
        // a full tile of MFMA ago) has landed; all waves past reads of buf^1.
        __syncthreads();
        if (t + 1 < NT) SC_STAGE(cur ^ 1, (t + 1) * 32);

        f16x8 bh[4], bl[4];
#pragma unroll
        for (int j = 0; j < 4; j++) {
            bh[j] = *(const f16x8*)&Bs_hi[cur][roB[j]];
            bl[j] = *(const f16x8*)&Bs_lo[cur][roB[j]];
        }
#pragma unroll
        for (int h = 0; h < 2; h++) {
            f16x8 ah[4], al[4];
#pragma unroll
            for (int i = 0; i < 4; i++) {
                ah[i] = *(const f16x8*)&As_hi[cur][roA[h * 4 + i]];
                al[i] = *(const f16x8*)&As_lo[cur][roA[h * 4 + i]];
            }
            __builtin_amdgcn_s_setprio(1);
#pragma unroll
            for (int i = 0; i < 4; i++)
#pragma unroll
                for (int j = 0; j < 4; j++)
                    acc[h * 4 + i][j] = __builtin_amdgcn_mfma_f32_16x16x32_f16(
                        ah[i], bh[j], acc[h * 4 + i][j], 0, 0, 0);
#pragma unroll
            for (int i = 0; i < 4; i++)
#pragma unroll
                for (int j = 0; j < 4; j++)
                    acc[h * 4 + i][j] = __builtin_amdgcn_mfma_f32_16x16x32_f16(
                        ah[i], bl[j], acc[h * 4 + i][j], 0, 0, 0);
#pragma unroll
            for (int i = 0; i < 4; i++)
#pragma unroll
                for (int j = 0; j < 4; j++)
                    acc[h * 4 + i][j] = __builtin_amdgcn_mfma_f32_16x16x32_f16(
                        al[i], bh[j], acc[h * 4 + i][j], 0, 0, 0);
            __builtin_amdgcn_s_setprio(0);
        }
    }
#undef SC_STAGE

    // Epilogue: f32 C write. C/D frag: col = lane&15, row = (lane>>4)*4 + reg.
    const int cr = fg * 4;
#pragma unroll
    for (int i = 0; i < 8; i++) {
#pragma unroll
        for (int j = 0; j < 4; j++) {
#pragma unroll
            for (int r = 0; r < 4; r++) {
                long mg = m0 + wrM + i * 16 + cr + r;
                long ng = n0 + wrN + j * 16 + fm;
                C[cOfs + mg * (long)ldc + ng] = acc[i][j][r];
            }
        }
    }

    // Fused column-softmax partials over this tile's 256 q-rows.
    __shared__ float stM[2][256];
    __shared__ float stS[2][256];
#pragma unroll
    for (int j = 0; j < 4; j++) {
        float mj = -3.402823466e38f;
#pragma unroll
        for (int i = 0; i < 8; i++)
#pragma unroll
            for (int r = 0; r < 4; r++) mj = fmaxf(mj, acc[i][j][r]);
        float sj = 0.f;
#pragma unroll
        for (int i = 0; i < 8; i++)
#pragma unroll
            for (int r = 0; r < 4; r++) sj += __expf(acc[i][j][r] - mj);
#pragma unroll
        for (int mask = 16; mask <= 32; mask <<= 1) {
            float mo = __shfl_xor(mj, mask, 64);
            float so = __shfl_xor(sj, mask, 64);
            float mn = fmaxf(mj, mo);
            sj = sj * __expf(mj - mn) + so * __expf(mo - mn);
            mj = mn;
        }
        if (fg == 0) {
            stM[rw][wrN + j * 16 + fm] = mj;
            stS[rw][wrN + j * 16 + fm] = sj;
        }
    }
    __syncthreads();
    if (tid < 256) {
        float ma = stM[0][tid], mb = stM[1][tid];
        float Mc = fmaxf(ma, mb);
        float Sv = stS[0][tid] * __expf(ma - Mc) + stS[1][tid] * __expf(mb - Mc);
        long o = ((long)z * (M >> 8) + blockIdx.y) * (long)Nc + (long)blockIdx.x * 256 + tid;
        pmOut[o] = Mc;
        psOut[o] = Sv;
    }
}

// Elementwise f32 -> f16 hi (+ optional lo) split. n multiple of 2048.
template<bool HAS_LO>
__global__ __launch_bounds__(256)
void split_kernel(const float* __restrict__ src, f16* __restrict__ hi,
                  f16* __restrict__ lo, long n)
{
    long i = ((long)blockIdx.x * 256 + threadIdx.x) * 8;
    if (i >= n) return;
    float4 x0 = *(const float4*)&src[i];
    float4 x1 = *(const float4*)&src[i + 4];
    float xs[8] = {x0.x, x0.y, x0.z, x0.w, x1.x, x1.y, x1.z, x1.w};
    f16x8 h, l;
#pragma unroll
    for (int e = 0; e < 8; e++) {
        f16 hh = (f16)xs[e];
        h[e] = hh;
        if (HAS_LO) l[e] = (f16)(xs[e] - (float)hh);
    }
    *(f16x8*)&hi[i] = h;
    if (HAS_LO) *(f16x8*)&lo[i] = l;
}

// Fold the CH q-chunk partials -> m[k], r[k] = 1/sum.
template<int CH>
__global__ __launch_bounds__(64)
void stats_combine_kernel(const float* __restrict__ pm, const float* __restrict__ ps,
                          float* __restrict__ statM, float* __restrict__ statR, int S)
{
    const int n = blockIdx.y;
    const int kk = blockIdx.x * 64 + threadIdx.x;
    float M = -INFINITY;
#pragma unroll
    for (int i = 0; i < CH; i++)
        M = fmaxf(M, pm[((long)n * CH + i) * S + kk]);
    float Ssum = 0.f;
#pragma unroll
    for (int i = 0; i < CH; i++)
        Ssum += ps[((long)n * CH + i) * S + kk] * __expf(pm[((long)n * CH + i) * S + kk] - M);
    statM[(long)n * S + kk] = M;
    statR[(long)n * S + kk] = 1.0f / Ssum;
}

// P_hi = (f16)(exp(Sc - m[k]) * r[k]).  Grid: (S/1024, S/32, N); thread = 4 k cols.
__global__ __launch_bounds__(256)
void pmat_kernel(const float* __restrict__ Sc, const float* __restrict__ statM,
                 const float* __restrict__ statR, f16* __restrict__ Phi, int S)
{
    const int n = blockIdx.z;
    const int kk = blockIdx.x * 1024 + threadIdx.x * 4;
    const float* Sn = Sc + (long)n * S * S;
    f16* ph = Phi + (long)n * S * S;
    float4 M4 = *(const float4*)&statM[(long)n * S + kk];
    float4 R4 = *(const float4*)&statR[(long)n * S + kk];
    const int q0 = blockIdx.y * 32;
    for (int qi = 0; qi < 32; qi++) {
        long idx = (long)(q0 + qi) * S + kk;
        float4 x = *(const float4*)&Sn[idx];
        f16x4 p;
        p[0] = (f16)(__expf(x.x - M4.x) * R4.x);
        p[1] = (f16)(__expf(x.y - M4.y) * R4.y);
        p[2] = (f16)(__expf(x.z - M4.z) * R4.z);
        p[3] = (f16)(__expf(x.w - M4.w) * R4.w);
        *(f16x4*)&ph[idx] = p;
    }
}

extern "C" void kernel_launch(void* const* d_in, const int* in_sizes, int n_in,
                              void* d_out, int out_size, void* d_ws, size_t ws_size,
                              hipStream_t stream)
{
    const float* v  = (const float*)d_in[0];
    const float* k  = (const float*)d_in[1];
    const float* q  = (const float*)d_in[2];
    const float* WV = (const float*)d_in[3];
    const float* WQ = (const float*)d_in[4];
    const float* WK = (const float*)d_in[5];
    float* out = (float*)d_out;

    const int N = 4, S = 2048, D = 1024;
    const long NSD = (long)N * S * D;   // 8388608
    const long DD  = (long)D * D;       // 1048576

    f16* ws = (f16*)d_ws;
    // phase-1 buffers
    f16* q_hi = ws;                 // [0,1)N
    f16* q_lo = ws + NSD;           // [1,2)N
    f16* k_hi = ws + 2 * NSD;
    f16* k_lo = ws + 3 * NSD;
    f16* v_hi = ws + 4 * NSD;
    f16* Wb   = ws + 5 * NSD;       // weight planes
    f16* WQ_hi = Wb,          *WQ_lo = Wb + DD;
    f16* WK_hi = Wb + 2 * DD, *WK_lo = Wb + 3 * DD;
    f16* WV_hi = Wb + 4 * DD;
    // projection outputs
    f16* wq_hi = ws + 5 * NSD + 5 * DD;
    f16* wq_lo = wq_hi + NSD;
    f16* wk_hi = wq_hi + 2 * NSD;
    f16* wk_lo = wq_hi + 3 * NSD;
    // aliases (lifetime-checked):
    f16* wvT_hi = ws;                       // [0,1)N — q_hi dead after q-proj
    float* Sc   = (float*)(ws + NSD);       // [1,5)N — q_lo/k/v dead by scores
    f16* P_hi   = wq_hi;                    // wq/wk dead after scores
    // stats: pm/ps are now [N][8][S] (256^2 scores tile => 8 q-chunks)
    float* pm    = (float*)(ws + 9 * NSD + 5 * DD);
    float* ps    = pm + (long)N * 8 * S;
    float* statM = ps + (long)N * 8 * S;
    float* statR = statM + (long)N * S;

    dim3 blk(256);

    // ---- split pre-pass ----
    split_kernel<true ><<<dim3(NSD / 2048), blk, 0, stream>>>(q,  q_hi, q_lo, NSD);
    split_kernel<true ><<<dim3(NSD / 2048), blk, 0, stream>>>(k,  k_hi, k_lo, NSD);
    split_kernel<false><<<dim3(NSD / 2048), blk, 0, stream>>>(v,  v_hi, nullptr, NSD);
    split_kernel<true ><<<dim3(DD / 2048),  blk, 0, stream>>>(WQ, WQ_hi, WQ_lo, DD);
    split_kernel<true ><<<dim3(DD / 2048),  blk, 0, stream>>>(WK, WK_hi, WK_lo, DD);
    split_kernel<false><<<dim3(DD / 2048),  blk, 0, stream>>>(WV, WV_hi, nullptr, DD);

    // ---- projections: M = N*S folded, C = X @ W^T ----
    {
        dim3 g(D / 128, (N * S) / 128, 1);
        mfma_gemm<SM_PLANES2, SM_PLANES2, EPI_SPLIT, 4, false><<<g, blk, 0, stream>>>(
            q_hi, q_lo, WQ_hi, WQ_lo, nullptr, nullptr, wq_hi, wq_lo,
            N * S, D, D, D, D, D, 0, 0, 0, 1.0f, 0);
        mfma_gemm<SM_PLANES2, SM_PLANES2, EPI_SPLIT, 4, false><<<g, blk, 0, stream>>>(
            k_hi, k_lo, WK_hi, WK_lo, nullptr, nullptr, wk_hi, wk_lo,
            N * S, D, D, D, D, D, 0, 0, 0, 1.0f, 0);
        mfma_gemm<SM_PLANES1, SM_PLANES1, EPI_F16T, 4, false><<<g, blk, 0, stream>>>(
            v_hi, nullptr, WV_hi, nullptr, nullptr, nullptr, wvT_hi, nullptr,
            N * S, D, D, D, D, 0, 0, 0, 0, 1.0f, 11 /* tsShift: S=2048 */);
    }
    // ---- scores: Sc[n] = wq[n] @ wk[n]^T (f32) + fused column-stat partials ----
    // 256^2 deep-pipelined kernel: grid (8,8,4) = 256 blocks = 1/CU.
    {
        dim3 g(S / 256, S / 256, N);
        scores_gemm<<<g, dim3(512), 0, stream>>>(
            wq_hi, wq_lo, wk_hi, wk_lo, pm, ps, Sc,
            S, S, D, D, D, S, (long)S * D, (long)S * D, (long)S * S);
    }
    // ---- combine partials -> statM, statR ----
    {
        dim3 gB(S / 64, N);
        stats_combine_kernel<8><<<gB, dim3(64), 0, stream>>>(pm, ps, statM, statR, S);
    }
    // ---- P_hi = exp(Sc - m)*r ----
    {
        dim3 g(S / 1024, S / 32, N);
        pmat_kernel<<<g, blk, 0, stream>>>(Sc, statM, statR, P_hi, S);
    }
    // ---- out[n] = (P[n] @ wvT[n]^T) / 1024 ----
    {
        dim3 g(D / 128, S / 128, N);
        mfma_gemm<SM_PLANES1, SM_PLANES1, EPI_F32, 4, false><<<g, blk, 0, stream>>>(
            P_hi, nullptr, wvT_hi, nullptr, nullptr, nullptr, out, nullptr,
            S, D, S, S, S, D, (long)S * S, (long)S * D, (long)S * D, 1.0f / (float)D, 0);
    }
}

// Round 2
// 458.998 us; speedup vs baseline: 1.0301x; 1.0301x over previous
//
#include <hip/hip_runtime.h>
#include <math.h>

// N=4, S=2048, D=1024, fp32 in/out.
// Pipeline (ALL GEMMs are GLL-staged f16-plane MFMA; conversion happens once in a pre-pass):
//   split   : q,k -> hi/lo planes ; v,WV -> hi ; WQ,WK -> hi/lo
//   wq = q@WQt, wk = k@WKt : triple-product (hh+hl+lh) GLL GEMM, split-plane out (128^2 template)
//   wvT = (v@WVt)^T        : single-product GLL GEMM, f16 hi transposed out [n][o][s]
//   Sc = wq@wkt            : 256^2 triple GLL GEMM, depth-2 counted-vmcnt pipeline,
//                            XCD-chunked block mapping, f32 out + fused column stats
//   combine                : fold 8 q-chunk partials -> m[k], r[k]=1/sum
//   pmat                   : P_hi = (f16) exp(Sc - m[k]) * r[k]
//   out = (P @ wvT^T)/1024 : single-product GLL GEMM, f32 out
// Workspace (f16 units, NSD = 8388608, DD = 1048576; peak < 10*NSD budget):
//   [0,1)N      q_hi   ; later wvT_hi (q dead after q-proj)
//   [1,2)N      q_lo   ; later Sc f32 spans [1,5)N (q_lo/k/v dead by then)
//   [2,4)N      k_hi|k_lo
//   [4,5)N      v_hi
//   [5N,5N+5DD) WQ_hi|WQ_lo|WK_hi|WK_lo|WV_hi
//   [5N+5DD, 9N+5DD) wq_hi|wq_lo|wk_hi|wk_lo ; later P_hi aliases wq_hi..(2N)
//   [9N+5DD, ..) stats (pm|ps|statM|statR, ~0.6 MB)

typedef _Float16 f16;
typedef _Float16 f16x8 __attribute__((ext_vector_type(8)));
typedef _Float16 f16x4 __attribute__((ext_vector_type(4)));
typedef float f32x4 __attribute__((ext_vector_type(4)));

enum StageMode { SM_PLANES2, SM_PLANES1 };
enum EpiMode   { EPI_F32, EPI_SPLIT, EPI_F16T };

#define GLL_PITCH 32   // f16 units/row; unpadded, XOR-swizzled 16B chunks

// async global->LDS, 16B per lane; LDS dest = wave-uniform base + lane*16
__device__ __forceinline__ void gll16(const f16* g, f16* l) {
    __builtin_amdgcn_global_load_lds(
        (const __attribute__((address_space(1))) void*)g,
        (__attribute__((address_space(3))) void*)l, 16, 0, 0);
}

// Stage one 128x32 f16 plane via GLL with XOR chunk swizzle (4-wave version, old template).
// Physical 16B slot t holds data (row = t>>2, chunk = (t&3) ^ ((row>>1)&3)).
__device__ __forceinline__ void stage_gll_plane(const f16* __restrict__ gplane,
                                                f16* __restrict__ lds,
                                                long rowBase, int ld, int k0,
                                                int wave, int lane)
{
#pragma unroll
    for (int i = 0; i < 2; i++) {
        int slotBase = (wave * 2 + i) * 64;
        int t = slotBase + lane;
        int r = t >> 2;
        int c = (t & 3) ^ ((r >> 1) & 3);
        const f16* g = gplane + (rowBase + r) * (long)ld + k0 + c * 8;
        gll16(g, lds + (long)slotBase * 8);   // wave-uniform LDS base
    }
}

__device__ __forceinline__ int frag_off_gll(int row, int g) {
    return row * GLL_PITCH + ((g ^ ((row >> 1) & 3)) << 3);
}

// ---------------------------------------------------------------------------
// Old 128x128 template (projections + final GEMM).
// C = A * B^T. A: [M,K], B: [Nc,K] row-major f16 planes (per batch plane).
// Tile 128x128, BK=32, 256 threads = 4 waves, each wave 64x64 (4x4 of 16x16x32).
template<StageMode SA, StageMode SB, EpiMode EP, int GROUPM, bool STATS>
__global__ __launch_bounds__(256, 4)
void mfma_gemm(const f16* __restrict__ Ahi, const f16* __restrict__ Alo,
               const f16* __restrict__ Bhi, const f16* __restrict__ Blo,
               float* __restrict__ pmOut, float* __restrict__ psOut,
               void* __restrict__ C0, void* __restrict__ C1,
               int M, int Nc, int K, int lda, int ldb, int ldc,
               long batchA, long batchB, long batchC,
               float epiScale, int tsShift)
{
    constexpr bool TRIPLE = (SA == SM_PLANES2);
    constexpr int PLANE_SZ = 128 * GLL_PITCH;

    int bx, by;
    if constexpr (GROUPM > 0) {
        int gx = gridDim.x;
        int lin = blockIdx.y * gx + blockIdx.x;
        int nig = GROUPM * gx;
        int gid = lin / nig;
        int rem = lin - gid * nig;
        by = gid * GROUPM + (rem % GROUPM);
        bx = rem / GROUPM;
    } else {
        bx = blockIdx.x;
        by = blockIdx.y;
    }
    const int n0 = bx * 128;
    const int m0 = by * 128;
    const long z = blockIdx.z;

    const long aOfs = z * batchA, bOfs = z * batchB, cOfs = z * batchC;

    __shared__ __align__(16) f16 As_hi[PLANE_SZ];
    __shared__ __align__(16) f16 Bs_hi[PLANE_SZ];
    __shared__ __align__(16) f16 As_lo[TRIPLE ? PLANE_SZ : 8];
    __shared__ __align__(16) f16 Bs_lo[TRIPLE ? PLANE_SZ : 8];

    const int tid  = threadIdx.x;
    const int lane = tid & 63;
    const int wave = tid >> 6;
    const int wr = (wave >> 1) * 64;
    const int wc = (wave & 1) * 64;
    const int fm = lane & 15;
    const int fg = lane >> 4;        // k-chunk index 0..3

    f32x4 acc[4][4];
#pragma unroll
    for (int i = 0; i < 4; i++)
#pragma unroll
        for (int j = 0; j < 4; j++) acc[i][j] = (f32x4){0.f, 0.f, 0.f, 0.f};

    int roA[4], roB[4];
#pragma unroll
    for (int i = 0; i < 4; i++) {
        roA[i] = frag_off_gll(wr + i * 16 + fm, fg);
        roB[i] = frag_off_gll(wc + i * 16 + fm, fg);
    }

    for (int k0 = 0; k0 < K; k0 += 32) {
        stage_gll_plane(Ahi + aOfs, As_hi, m0, lda, k0, wave, lane);
        stage_gll_plane(Bhi + bOfs, Bs_hi, n0, ldb, k0, wave, lane);
        if constexpr (TRIPLE) {
            stage_gll_plane(Alo + aOfs, As_lo, m0, lda, k0, wave, lane);
            stage_gll_plane(Blo + bOfs, Bs_lo, n0, ldb, k0, wave, lane);
        }
        __syncthreads();

        f16x8 ah[4], bh[4], al[4], bl[4];
#pragma unroll
        for (int i = 0; i < 4; i++) {
            ah[i] = *(const f16x8*)&As_hi[roA[i]];
            bh[i] = *(const f16x8*)&Bs_hi[roB[i]];
            if constexpr (TRIPLE) {
                al[i] = *(const f16x8*)&As_lo[roA[i]];
                bl[i] = *(const f16x8*)&Bs_lo[roB[i]];
            }
        }
#pragma unroll
        for (int i = 0; i < 4; i++) {
#pragma unroll
            for (int j = 0; j < 4; j++) {
                acc[i][j] = __builtin_amdgcn_mfma_f32_16x16x32_f16(ah[i], bh[j], acc[i][j], 0, 0, 0);
                if constexpr (TRIPLE) {
                    acc[i][j] = __builtin_amdgcn_mfma_f32_16x16x32_f16(ah[i], bl[j], acc[i][j], 0, 0, 0);
                    acc[i][j] = __builtin_amdgcn_mfma_f32_16x16x32_f16(al[i], bh[j], acc[i][j], 0, 0, 0);
                }
            }
        }
        __syncthreads();
    }

    // Epilogue. C/D frag: col = lane&15, row = (lane>>4)*4 + reg  [m89-verified]
    const int cr = fg * 4;
    const int cn = fm;
#pragma unroll
    for (int i = 0; i < 4; i++) {
#pragma unroll
        for (int j = 0; j < 4; j++) {
#pragma unroll
            for (int r = 0; r < 4; r++) {
                long mg = m0 + wr + i * 16 + cr + r;
                long ng = n0 + wc + j * 16 + cn;
                float val = acc[i][j][r] * epiScale;
                if constexpr (EP == EPI_F32) {
                    ((float*)C0)[cOfs + mg * ldc + ng] = val;
                } else if constexpr (EP == EPI_SPLIT) {
                    f16 h = (f16)val;
                    ((f16*)C0)[cOfs + mg * ldc + ng] = h;
                    ((f16*)C1)[cOfs + mg * ldc + ng] = (f16)(val - (float)h);
                } else { // EPI_F16T: batch folded in M; write [nb][n][s], hi only
                    long TS = 1L << tsShift;
                    long nb = mg >> tsShift;
                    long s  = mg & (TS - 1);
                    long addr = nb * ((long)Nc << tsShift) + ng * TS + s;
                    ((f16*)C0)[addr] = (f16)val;
                }
            }
        }
    }

    if constexpr (STATS) {
        __shared__ float stM[2][128];
        __shared__ float stS[2][128];
#pragma unroll
        for (int j = 0; j < 4; j++) {
            float mj = -3.402823466e38f;
#pragma unroll
            for (int i = 0; i < 4; i++)
#pragma unroll
                for (int r = 0; r < 4; r++) mj = fmaxf(mj, acc[i][j][r]);
            float sj = 0.f;
#pragma unroll
            for (int i = 0; i < 4; i++)
#pragma unroll
                for (int r = 0; r < 4; r++) sj += __expf(acc[i][j][r] - mj);
#pragma unroll
            for (int mask = 16; mask <= 32; mask <<= 1) {
                float mo = __shfl_xor(mj, mask, 64);
                float so = __shfl_xor(sj, mask, 64);
                float mn = fmaxf(mj, mo);
                sj = sj * __expf(mj - mn) + so * __expf(mo - mn);
                mj = mn;
            }
            if (fg == 0) {
                stM[wave >> 1][wc + j * 16 + cn] = mj;
                stS[wave >> 1][wc + j * 16 + cn] = sj;
            }
        }
        __syncthreads();
        if (tid < 128) {
            float ma = stM[0][tid], mb = stM[1][tid];
            float Mc = fmaxf(ma, mb);
            float Sv = stS[0][tid] * __expf(ma - Mc) + stS[1][tid] * __expf(mb - Mc);
            long o = ((long)z * (M >> 7) + by) * (long)Nc + (long)bx * 128 + tid;
            pmOut[o] = Mc;
            psOut[o] = Sv;
        }
    }
}

// ---------------------------------------------------------------------------
// 256x256 scores GEMM, depth-2 counted-vmcnt pipeline + XCD-chunked mapping.
// C = A @ B^T per batch, triple-product f16 split planes, BK=32,
// 512 threads = 8 waves (2M x 4N), per-wave 128x64.
//
// Measured diagnosis (round 1): latency/MLP-bound on the staging stream
// (512 MB input stream at only ~4.8 TB/s effective; per-tile time == stream
// time; vmcnt(0)-per-tile drained in-flight loads to zero at every barrier).
// Schedule now:
//   prologue: stage tiles 0 and 1 (16 loads/thread in flight)
//   per tile: s_waitcnt vmcnt(8)  (counted — NEVER 0 until last tile)
//             s_barrier
//             ds_read ALL frags of buf cur (B hoisted, A in two halves)
//             lgkmcnt(0) ; s_barrier      (all waves done reading buf cur)
//             re-stage buf cur with tile t+2   (loads get 2 full tiles to land)
//             MFMA h1 cluster
// XCD mapping: XCD j owns all 8 bx x 4 (by,z) pairs -> each A panel is read by
// exactly one XCD (8 L2-served reuses), each B panel by two.
__global__ __launch_bounds__(512, 2)
void scores_gemm(const f16* __restrict__ Ahi, const f16* __restrict__ Alo,
                 const f16* __restrict__ Bhi, const f16* __restrict__ Blo,
                 float* __restrict__ pmOut, float* __restrict__ psOut,
                 float* __restrict__ C,
                 int M, int Nc, int K, int lda, int ldb, int ldc,
                 long batchA, long batchB, long batchC)
{
    constexpr int PLANE = 256 * GLL_PITCH;   // 8192 f16 = 16 KB

    __shared__ __align__(16) f16 As_hi[2][PLANE];
    __shared__ __align__(16) f16 As_lo[2][PLANE];
    __shared__ __align__(16) f16 Bs_hi[2][PLANE];
    __shared__ __align__(16) f16 Bs_lo[2][PLANE];

    const int tid  = threadIdx.x;
    const int lane = tid & 63;
    const int wave = tid >> 6;
    const int rw   = wave >> 2;      // 0..1 : row half (128 rows)
    const int cw   = wave & 3;       // 0..3 : col quarter (64 cols)
    const int wrM  = rw * 128;
    const int wrN  = cw * 64;
    const int fm   = lane & 15;
    const int fg   = lane >> 4;      // k-chunk index 0..3

    // XCD-chunked remap. Grid is (8,8,4) = 256 blocks, 1/CU; HW round-robins
    // linear id % 8 across XCDs. XCD j gets s=0..31: bx = s&7 (all 8),
    // (by,z) from idx = j*4 + (s>>3) -> 4 pairs, disjoint across XCDs.
    const int Lid = (int)(blockIdx.z * 64 + blockIdx.y * 8 + blockIdx.x);
    const int xcd = Lid & 7;
    const int sct = Lid >> 3;
    const int bxn = sct & 7;
    const int idxp = xcd * 4 + (sct >> 3);
    const int byn = idxp & 7;
    const int zn  = idxp >> 3;

    const int n0 = bxn * 256;
    const int m0 = byn * 256;
    const long z = zn;
    const long aOfs = z * batchA, bOfs = z * batchB, cOfs = z * batchC;

    // staging: 1024 16B slots per 256x32 plane; this thread owns two.
    // slot t holds (row = t>>2, chunk = (t&3) ^ ((row>>1)&3)).
    int slotBase[2], srcA[2], srcB[2];
#pragma unroll
    for (int i = 0; i < 2; i++) {
        int sb = (wave * 2 + i) * 64;        // wave-uniform slot base
        int t  = sb + lane;
        int r  = t >> 2;
        int c  = (t & 3) ^ ((r >> 1) & 3);
        slotBase[i] = sb * 8;                // f16 units
        srcA[i] = (m0 + r) * lda + c * 8;
        srcB[i] = (n0 + r) * ldb + c * 8;
    }

#define SC_STAGE(buf, k0) do {                                              \
    _Pragma("unroll")                                                        \
    for (int s_ = 0; s_ < 2; s_++) {                                         \
        gll16(Ahi + aOfs + srcA[s_] + (k0), &As_hi[buf][slotBase[s_]]);      \
        gll16(Alo + aOfs + srcA[s_] + (k0), &As_lo[buf][slotBase[s_]]);      \
        gll16(Bhi + bOfs + srcB[s_] + (k0), &Bs_hi[buf][slotBase[s_]]);      \
        gll16(Blo + bOfs + srcB[s_] + (k0), &Bs_lo[buf][slotBase[s_]]);      \
    } } while (0)

    f32x4 acc[8][4];
#pragma unroll
    for (int i = 0; i < 8; i++)
#pragma unroll
        for (int j = 0; j < 4; j++) acc[i][j] = (f32x4){0.f, 0.f, 0.f, 0.f};

    int roA[8], roB[4];
#pragma unroll
    for (int i = 0; i < 8; i++) roA[i] = frag_off_gll(wrM + i * 16 + fm, fg);
#pragma unroll
    for (int j = 0; j < 4; j++) roB[j] = frag_off_gll(wrN + j * 16 + fm, fg);

    const int NT = K >> 5;     // 32 K-tiles
    SC_STAGE(0, 0);            // tile 0 -> buf 0   (8 loads)
    SC_STAGE(1, 32);           // tile 1 -> buf 1   (16 loads in flight)

    for (int t = 0; t < NT; t++) {
        const int cur = t & 1;
        // Counted wait: tile t's 8 loads (issued 2 tiles ago) are the oldest
        // 8 of <=16 outstanding. Never drain to 0 in the main loop (T4).
        if (t < NT - 1) {
            asm volatile("s_waitcnt vmcnt(8)" ::: "memory");
        } else {
            asm volatile("s_waitcnt vmcnt(0)" ::: "memory");
        }
        __builtin_amdgcn_sched_barrier(0);
        __builtin_amdgcn_s_barrier();
        __builtin_amdgcn_sched_barrier(0);

        // ---- consume buf cur ----
        f16x8 bh[4], bl[4], a0h[4], a0l[4];
#pragma unroll
        for (int j = 0; j < 4; j++) {
            bh[j] = *(const f16x8*)&Bs_hi[cur][roB[j]];
            bl[j] = *(const f16x8*)&Bs_lo[cur][roB[j]];
        }
#pragma unroll
        for (int i = 0; i < 4; i++) {
            a0h[i] = *(const f16x8*)&As_hi[cur][roA[i]];
            a0l[i] = *(const f16x8*)&As_lo[cur][roA[i]];
        }
        __builtin_amdgcn_s_setprio(1);
#pragma unroll
        for (int i = 0; i < 4; i++)
#pragma unroll
            for (int j = 0; j < 4; j++)
                acc[i][j] = __builtin_amdgcn_mfma_f32_16x16x32_f16(a0h[i], bh[j], acc[i][j], 0, 0, 0);
#pragma unroll
        for (int i = 0; i < 4; i++)
#pragma unroll
            for (int j = 0; j < 4; j++)
                acc[i][j] = __builtin_amdgcn_mfma_f32_16x16x32_f16(a0h[i], bl[j], acc[i][j], 0, 0, 0);
#pragma unroll
        for (int i = 0; i < 4; i++)
#pragma unroll
            for (int j = 0; j < 4; j++)
                acc[i][j] = __builtin_amdgcn_mfma_f32_16x16x32_f16(a0l[i], bh[j], acc[i][j], 0, 0, 0);
        __builtin_amdgcn_s_setprio(0);

        // second A half read BEFORE re-stage of buf cur (no LDS read/write race)
        f16x8 a1h[4], a1l[4];
#pragma unroll
        for (int i = 0; i < 4; i++) {
            a1h[i] = *(const f16x8*)&As_hi[cur][roA[4 + i]];
            a1l[i] = *(const f16x8*)&As_lo[cur][roA[4 + i]];
        }
        asm volatile("s_waitcnt lgkmcnt(0)" ::: "memory");
        __builtin_amdgcn_sched_barrier(0);
        __builtin_amdgcn_s_barrier();     // all waves done reading buf cur
        __builtin_amdgcn_sched_barrier(0);

        if (t + 2 < NT) SC_STAGE(cur, (t + 2) * 32);   // refill buf cur

        __builtin_amdgcn_s_setprio(1);
#pragma unroll
        for (int i = 0; i < 4; i++)
#pragma unroll
            for (int j = 0; j < 4; j++)
                acc[4 + i][j] = __builtin_amdgcn_mfma_f32_16x16x32_f16(a1h[i], bh[j], acc[4 + i][j], 0, 0, 0);
#pragma unroll
        for (int i = 0; i < 4; i++)
#pragma unroll
            for (int j = 0; j < 4; j++)
                acc[4 + i][j] = __builtin_amdgcn_mfma_f32_16x16x32_f16(a1h[i], bl[j], acc[4 + i][j], 0, 0, 0);
#pragma unroll
        for (int i = 0; i < 4; i++)
#pragma unroll
            for (int j = 0; j < 4; j++)
                acc[4 + i][j] = __builtin_amdgcn_mfma_f32_16x16x32_f16(a1l[i], bh[j], acc[4 + i][j], 0, 0, 0);
        __builtin_amdgcn_s_setprio(0);
    }
#undef SC_STAGE

    // Epilogue: f32 C write. C/D frag: col = lane&15, row = (lane>>4)*4 + reg.
    const int cr = fg * 4;
#pragma unroll
    for (int i = 0; i < 8; i++) {
#pragma unroll
        for (int j = 0; j < 4; j++) {
#pragma unroll
            for (int r = 0; r < 4; r++) {
                long mg = m0 + wrM + i * 16 + cr + r;
                long ng = n0 + wrN + j * 16 + fm;
                C[cOfs + mg * (long)ldc + ng] = acc[i][j][r];
            }
        }
    }

    // Fused column-softmax partials over this tile's 256 q-rows.
    __shared__ float stM[2][256];
    __shared__ float stS[2][256];
#pragma unroll
    for (int j = 0; j < 4; j++) {
        float mj = -3.402823466e38f;
#pragma unroll
        for (int i = 0; i < 8; i++)
#pragma unroll
            for (int r = 0; r < 4; r++) mj = fmaxf(mj, acc[i][j][r]);
        float sj = 0.f;
#pragma unroll
        for (int i = 0; i < 8; i++)
#pragma unroll
            for (int r = 0; r < 4; r++) sj += __expf(acc[i][j][r] - mj);
#pragma unroll
        for (int mask = 16; mask <= 32; mask <<= 1) {
            float mo = __shfl_xor(mj, mask, 64);
            float so = __shfl_xor(sj, mask, 64);
            float mn = fmaxf(mj, mo);
            sj = sj * __expf(mj - mn) + so * __expf(mo - mn);
            mj = mn;
        }
        if (fg == 0) {
            stM[rw][wrN + j * 16 + fm] = mj;
            stS[rw][wrN + j * 16 + fm] = sj;
        }
    }
    __syncthreads();
    if (tid < 256) {
        float ma = stM[0][tid], mb = stM[1][tid];
        float Mc = fmaxf(ma, mb);
        float Sv = stS[0][tid] * __expf(ma - Mc) + stS[1][tid] * __expf(mb - Mc);
        long o = ((long)z * (M >> 8) + byn) * (long)Nc + (long)bxn * 256 + tid;
        pmOut[o] = Mc;
        psOut[o] = Sv;
    }
}

// Elementwise f32 -> f16 hi (+ optional lo) split. n multiple of 2048.
template<bool HAS_LO>
__global__ __launch_bounds__(256)
void split_kernel(const float* __restrict__ src, f16* __restrict__ hi,
                  f16* __restrict__ lo, long n)
{
    long i = ((long)blockIdx.x * 256 + threadIdx.x) * 8;
    if (i >= n) return;
    float4 x0 = *(const float4*)&src[i];
    float4 x1 = *(const float4*)&src[i + 4];
    float xs[8] = {x0.x, x0.y, x0.z, x0.w, x1.x, x1.y, x1.z, x1.w};
    f16x8 h, l;
#pragma unroll
    for (int e = 0; e < 8; e++) {
        f16 hh = (f16)xs[e];
        h[e] = hh;
        if (HAS_LO) l[e] = (f16)(xs[e] - (float)hh);
    }
    *(f16x8*)&hi[i] = h;
    if (HAS_LO) *(f16x8*)&lo[i] = l;
}

// Fold the CH q-chunk partials -> m[k], r[k] = 1/sum.
template<int CH>
__global__ __launch_bounds__(64)
void stats_combine_kernel(const float* __restrict__ pm, const float* __restrict__ ps,
                          float* __restrict__ statM, float* __restrict__ statR, int S)
{
    const int n = blockIdx.y;
    const int kk = blockIdx.x * 64 + threadIdx.x;
    float M = -INFINITY;
#pragma unroll
    for (int i = 0; i < CH; i++)
        M = fmaxf(M, pm[((long)n * CH + i) * S + kk]);
    float Ssum = 0.f;
#pragma unroll
    for (int i = 0; i < CH; i++)
        Ssum += ps[((long)n * CH + i) * S + kk] * __expf(pm[((long)n * CH + i) * S + kk] - M);
    statM[(long)n * S + kk] = M;
    statR[(long)n * S + kk] = 1.0f / Ssum;
}

// P_hi = (f16)(exp(Sc - m[k]) * r[k]).  Grid: (S/1024, S/32, N); thread = 4 k cols.
__global__ __launch_bounds__(256)
void pmat_kernel(const float* __restrict__ Sc, const float* __restrict__ statM,
                 const float* __restrict__ statR, f16* __restrict__ Phi, int S)
{
    const int n = blockIdx.z;
    const int kk = blockIdx.x * 1024 + threadIdx.x * 4;
    const float* Sn = Sc + (long)n * S * S;
    f16* ph = Phi + (long)n * S * S;
    float4 M4 = *(const float4*)&statM[(long)n * S + kk];
    float4 R4 = *(const float4*)&statR[(long)n * S + kk];
    const int q0 = blockIdx.y * 32;
    for (int qi = 0; qi < 32; qi++) {
        long idx = (long)(q0 + qi) * S + kk;
        float4 x = *(const float4*)&Sn[idx];
        f16x4 p;
        p[0] = (f16)(__expf(x.x - M4.x) * R4.x);
        p[1] = (f16)(__expf(x.y - M4.y) * R4.y);
        p[2] = (f16)(__expf(x.z - M4.z) * R4.z);
        p[3] = (f16)(__expf(x.w - M4.w) * R4.w);
        *(f16x4*)&ph[idx] = p;
    }
}

extern "C" void kernel_launch(void* const* d_in, const int* in_sizes, int n_in,
                              void* d_out, int out_size, void* d_ws, size_t ws_size,
                              hipStream_t stream)
{
    const float* v  = (const float*)d_in[0];
    const float* k  = (const float*)d_in[1];
    const float* q  = (const float*)d_in[2];
    const float* WV = (const float*)d_in[3];
    const float* WQ = (const float*)d_in[4];
    const float* WK = (const float*)d_in[5];
    float* out = (float*)d_out;

    const int N = 4, S = 2048, D = 1024;
    const long NSD = (long)N * S * D;   // 8388608
    const long DD  = (long)D * D;       // 1048576

    f16* ws = (f16*)d_ws;
    // phase-1 buffers
    f16* q_hi = ws;                 // [0,1)N
    f16* q_lo = ws + NSD;           // [1,2)N
    f16* k_hi = ws + 2 * NSD;
    f16* k_lo = ws + 3 * NSD;
    f16* v_hi = ws + 4 * NSD;
    f16* Wb   = ws + 5 * NSD;       // weight planes
    f16* WQ_hi = Wb,          *WQ_lo = Wb + DD;
    f16* WK_hi = Wb + 2 * DD, *WK_lo = Wb + 3 * DD;
    f16* WV_hi = Wb + 4 * DD;
    // projection outputs
    f16* wq_hi = ws + 5 * NSD + 5 * DD;
    f16* wq_lo = wq_hi + NSD;
    f16* wk_hi = wq_hi + 2 * NSD;
    f16* wk_lo = wq_hi + 3 * NSD;
    // aliases (lifetime-checked):
    f16* wvT_hi = ws;                       // [0,1)N — q_hi dead after q-proj
    float* Sc   = (float*)(ws + NSD);       // [1,5)N — q_lo/k/v dead by scores
    f16* P_hi   = wq_hi;                    // wq/wk dead after scores
    // stats: pm/ps are [N][8][S] (256^2 scores tile => 8 q-chunks)
    float* pm    = (float*)(ws + 9 * NSD + 5 * DD);
    float* ps    = pm + (long)N * 8 * S;
    float* statM = ps + (long)N * 8 * S;
    float* statR = statM + (long)N * S;

    dim3 blk(256);

    // ---- split pre-pass ----
    split_kernel<true ><<<dim3(NSD / 2048), blk, 0, stream>>>(q,  q_hi, q_lo, NSD);
    split_kernel<true ><<<dim3(NSD / 2048), blk, 0, stream>>>(k,  k_hi, k_lo, NSD);
    split_kernel<false><<<dim3(NSD / 2048), blk, 0, stream>>>(v,  v_hi, nullptr, NSD);
    split_kernel<true ><<<dim3(DD / 2048),  blk, 0, stream>>>(WQ, WQ_hi, WQ_lo, DD);
    split_kernel<true ><<<dim3(DD / 2048),  blk, 0, stream>>>(WK, WK_hi, WK_lo, DD);
    split_kernel<false><<<dim3(DD / 2048),  blk, 0, stream>>>(WV, WV_hi, nullptr, DD);

    // ---- projections: M = N*S folded, C = X @ W^T ----
    {
        dim3 g(D / 128, (N * S) / 128, 1);
        mfma_gemm<SM_PLANES2, SM_PLANES2, EPI_SPLIT, 4, false><<<g, blk, 0, stream>>>(
            q_hi, q_lo, WQ_hi, WQ_lo, nullptr, nullptr, wq_hi, wq_lo,
            N * S, D, D, D, D, D, 0, 0, 0, 1.0f, 0);
        mfma_gemm<SM_PLANES2, SM_PLANES2, EPI_SPLIT, 4, false><<<g, blk, 0, stream>>>(
            k_hi, k_lo, WK_hi, WK_lo, nullptr, nullptr, wk_hi, wk_lo,
            N * S, D, D, D, D, D, 0, 0, 0, 1.0f, 0);
        mfma_gemm<SM_PLANES1, SM_PLANES1, EPI_F16T, 4, false><<<g, blk, 0, stream>>>(
            v_hi, nullptr, WV_hi, nullptr, nullptr, nullptr, wvT_hi, nullptr,
            N * S, D, D, D, D, 0, 0, 0, 0, 1.0f, 11 /* tsShift: S=2048 */);
    }
    // ---- scores: Sc[n] = wq[n] @ wk[n]^T (f32) + fused column-stat partials ----
    // 256^2 counted-vmcnt kernel: grid (8,8,4) = 256 blocks = 1/CU, XCD-chunked.
    {
        dim3 g(S / 256, S / 256, N);
        scores_gemm<<<g, dim3(512), 0, stream>>>(
            wq_hi, wq_lo, wk_hi, wk_lo, pm, ps, Sc,
            S, S, D, D, D, S, (long)S * D, (long)S * D, (long)S * S);
    }
    // ---- combine partials -> statM, statR ----
    {
        dim3 gB(S / 64, N);
        stats_combine_kernel<8><<<gB, dim3(64), 0, stream>>>(pm, ps, statM, statR, S);
    }
    // ---- P_hi = exp(Sc - m)*r ----
    {
        dim3 g(S / 1024, S / 32, N);
        pmat_kernel<<<g, blk, 0, stream>>>(Sc, statM, statR, P_hi, S);
    }
    // ---- out[n] = (P[n] @ wvT[n]^T) / 1024 ----
    {
        dim3 g(D / 128, S / 128, N);
        mfma_gemm<SM_PLANES1, SM_PLANES1, EPI_F32, 4, false><<<g, blk, 0, stream>>>(
            P_hi, nullptr, wvT_hi, nullptr, nullptr, nullptr, out, nullptr,
            S, D, S, S, S, D, (long)S * S, (long)S * D, (long)S * D, 1.0f / (float)D, 0);
    }
}

// Round 3
// 458.803 us; speedup vs baseline: 1.0305x; 1.0004x over previous
//
#include <hip/hip_runtime.h>
#include <math.h>

// N=4, S=2048, D=1024, fp32 in/out.
// Pipeline (ALL GEMMs are GLL-staged f16-plane MFMA; conversion happens once in a pre-pass):
//   split   : q,k -> hi/lo planes ; v,WV -> hi ; WQ,WK -> hi/lo
//   wq = q@WQt, wk = k@WKt : triple-product (hh+hl+lh) GLL GEMM, split-plane out (128^2 template)
//   wvT = (v@WVt)^T        : single-product GLL GEMM, f16 hi transposed out [n][o][s]
//   Sc = wq@wkt            : 256^2 triple GLL GEMM, depth-2 counted-vmcnt pipeline,
//                            XCD-chunked mapping, intra-tile ds_read/MFMA interleave,
//                            f32 out + fused column stats
//   combine                : fold 8 q-chunk partials -> m[k], r[k]=1/sum
//   pmat                   : P_hi = (f16) exp(Sc - m[k]) * r[k]
//   out = (P @ wvT^T)/1024 : single-product GLL GEMM, f32 out
// Workspace (f16 units, NSD = 8388608, DD = 1048576; peak < 10*NSD budget):
//   [0,1)N      q_hi   ; later wvT_hi (q dead after q-proj)
//   [1,2)N      q_lo   ; later Sc f32 spans [1,5)N (q_lo/k/v dead by then)
//   [2,4)N      k_hi|k_lo
//   [4,5)N      v_hi
//   [5N,5N+5DD) WQ_hi|WQ_lo|WK_hi|WK_lo|WV_hi
//   [5N+5DD, 9N+5DD) wq_hi|wq_lo|wk_hi|wk_lo ; later P_hi aliases wq_hi..(2N)
//   [9N+5DD, ..) stats (pm|ps|statM|statR, ~0.6 MB)

typedef _Float16 f16;
typedef _Float16 f16x8 __attribute__((ext_vector_type(8)));
typedef _Float16 f16x4 __attribute__((ext_vector_type(4)));
typedef float f32x4 __attribute__((ext_vector_type(4)));

enum StageMode { SM_PLANES2, SM_PLANES1 };
enum EpiMode   { EPI_F32, EPI_SPLIT, EPI_F16T };

#define GLL_PITCH 32   // f16 units/row; unpadded, XOR-swizzled 16B chunks

// async global->LDS, 16B per lane; LDS dest = wave-uniform base + lane*16
__device__ __forceinline__ void gll16(const f16* g, f16* l) {
    __builtin_amdgcn_global_load_lds(
        (const __attribute__((address_space(1))) void*)g,
        (__attribute__((address_space(3))) void*)l, 16, 0, 0);
}

// Stage one 128x32 f16 plane via GLL with XOR chunk swizzle (4-wave version, old template).
// Physical 16B slot t holds data (row = t>>2, chunk = (t&3) ^ ((row>>1)&3)).
__device__ __forceinline__ void stage_gll_plane(const f16* __restrict__ gplane,
                                                f16* __restrict__ lds,
                                                long rowBase, int ld, int k0,
                                                int wave, int lane)
{
#pragma unroll
    for (int i = 0; i < 2; i++) {
        int slotBase = (wave * 2 + i) * 64;
        int t = slotBase + lane;
        int r = t >> 2;
        int c = (t & 3) ^ ((r >> 1) & 3);
        const f16* g = gplane + (rowBase + r) * (long)ld + k0 + c * 8;
        gll16(g, lds + (long)slotBase * 8);   // wave-uniform LDS base
    }
}

__device__ __forceinline__ int frag_off_gll(int row, int g) {
    return row * GLL_PITCH + ((g ^ ((row >> 1) & 3)) << 3);
}

// ---------------------------------------------------------------------------
// Old 128x128 template (projections + final GEMM).
// C = A * B^T. A: [M,K], B: [Nc,K] row-major f16 planes (per batch plane).
// Tile 128x128, BK=32, 256 threads = 4 waves, each wave 64x64 (4x4 of 16x16x32).
template<StageMode SA, StageMode SB, EpiMode EP, int GROUPM, bool STATS>
__global__ __launch_bounds__(256, 4)
void mfma_gemm(const f16* __restrict__ Ahi, const f16* __restrict__ Alo,
               const f16* __restrict__ Bhi, const f16* __restrict__ Blo,
               float* __restrict__ pmOut, float* __restrict__ psOut,
               void* __restrict__ C0, void* __restrict__ C1,
               int M, int Nc, int K, int lda, int ldb, int ldc,
               long batchA, long batchB, long batchC,
               float epiScale, int tsShift)
{
    constexpr bool TRIPLE = (SA == SM_PLANES2);
    constexpr int PLANE_SZ = 128 * GLL_PITCH;

    int bx, by;
    if constexpr (GROUPM > 0) {
        int gx = gridDim.x;
        int lin = blockIdx.y * gx + blockIdx.x;
        int nig = GROUPM * gx;
        int gid = lin / nig;
        int rem = lin - gid * nig;
        by = gid * GROUPM + (rem % GROUPM);
        bx = rem / GROUPM;
    } else {
        bx = blockIdx.x;
        by = blockIdx.y;
    }
    const int n0 = bx * 128;
    const int m0 = by * 128;
    const long z = blockIdx.z;

    const long aOfs = z * batchA, bOfs = z * batchB, cOfs = z * batchC;

    __shared__ __align__(16) f16 As_hi[PLANE_SZ];
    __shared__ __align__(16) f16 Bs_hi[PLANE_SZ];
    __shared__ __align__(16) f16 As_lo[TRIPLE ? PLANE_SZ : 8];
    __shared__ __align__(16) f16 Bs_lo[TRIPLE ? PLANE_SZ : 8];

    const int tid  = threadIdx.x;
    const int lane = tid & 63;
    const int wave = tid >> 6;
    const int wr = (wave >> 1) * 64;
    const int wc = (wave & 1) * 64;
    const int fm = lane & 15;
    const int fg = lane >> 4;        // k-chunk index 0..3

    f32x4 acc[4][4];
#pragma unroll
    for (int i = 0; i < 4; i++)
#pragma unroll
        for (int j = 0; j < 4; j++) acc[i][j] = (f32x4){0.f, 0.f, 0.f, 0.f};

    int roA[4], roB[4];
#pragma unroll
    for (int i = 0; i < 4; i++) {
        roA[i] = frag_off_gll(wr + i * 16 + fm, fg);
        roB[i] = frag_off_gll(wc + i * 16 + fm, fg);
    }

    for (int k0 = 0; k0 < K; k0 += 32) {
        stage_gll_plane(Ahi + aOfs, As_hi, m0, lda, k0, wave, lane);
        stage_gll_plane(Bhi + bOfs, Bs_hi, n0, ldb, k0, wave, lane);
        if constexpr (TRIPLE) {
            stage_gll_plane(Alo + aOfs, As_lo, m0, lda, k0, wave, lane);
            stage_gll_plane(Blo + bOfs, Bs_lo, n0, ldb, k0, wave, lane);
        }
        __syncthreads();

        f16x8 ah[4], bh[4], al[4], bl[4];
#pragma unroll
        for (int i = 0; i < 4; i++) {
            ah[i] = *(const f16x8*)&As_hi[roA[i]];
            bh[i] = *(const f16x8*)&Bs_hi[roB[i]];
            if constexpr (TRIPLE) {
                al[i] = *(const f16x8*)&As_lo[roA[i]];
                bl[i] = *(const f16x8*)&Bs_lo[roB[i]];
            }
        }
#pragma unroll
        for (int i = 0; i < 4; i++) {
#pragma unroll
            for (int j = 0; j < 4; j++) {
                acc[i][j] = __builtin_amdgcn_mfma_f32_16x16x32_f16(ah[i], bh[j], acc[i][j], 0, 0, 0);
                if constexpr (TRIPLE) {
                    acc[i][j] = __builtin_amdgcn_mfma_f32_16x16x32_f16(ah[i], bl[j], acc[i][j], 0, 0, 0);
                    acc[i][j] = __builtin_amdgcn_mfma_f32_16x16x32_f16(al[i], bh[j], acc[i][j], 0, 0, 0);
                }
            }
        }
        __syncthreads();
    }

    // Epilogue. C/D frag: col = lane&15, row = (lane>>4)*4 + reg  [m89-verified]
    const int cr = fg * 4;
    const int cn = fm;
#pragma unroll
    for (int i = 0; i < 4; i++) {
#pragma unroll
        for (int j = 0; j < 4; j++) {
#pragma unroll
            for (int r = 0; r < 4; r++) {
                long mg = m0 + wr + i * 16 + cr + r;
                long ng = n0 + wc + j * 16 + cn;
                float val = acc[i][j][r] * epiScale;
                if constexpr (EP == EPI_F32) {
                    ((float*)C0)[cOfs + mg * ldc + ng] = val;
                } else if constexpr (EP == EPI_SPLIT) {
                    f16 h = (f16)val;
                    ((f16*)C0)[cOfs + mg * ldc + ng] = h;
                    ((f16*)C1)[cOfs + mg * ldc + ng] = (f16)(val - (float)h);
                } else { // EPI_F16T: batch folded in M; write [nb][n][s], hi only
                    long TS = 1L << tsShift;
                    long nb = mg >> tsShift;
                    long s  = mg & (TS - 1);
                    long addr = nb * ((long)Nc << tsShift) + ng * TS + s;
                    ((f16*)C0)[addr] = (f16)val;
                }
            }
        }
    }

    if constexpr (STATS) {
        __shared__ float stM[2][128];
        __shared__ float stS[2][128];
#pragma unroll
        for (int j = 0; j < 4; j++) {
            float mj = -3.402823466e38f;
#pragma unroll
            for (int i = 0; i < 4; i++)
#pragma unroll
                for (int r = 0; r < 4; r++) mj = fmaxf(mj, acc[i][j][r]);
            float sj = 0.f;
#pragma unroll
            for (int i = 0; i < 4; i++)
#pragma unroll
                for (int r = 0; r < 4; r++) sj += __expf(acc[i][j][r] - mj);
#pragma unroll
            for (int mask = 16; mask <= 32; mask <<= 1) {
                float mo = __shfl_xor(mj, mask, 64);
                float so = __shfl_xor(sj, mask, 64);
                float mn = fmaxf(mj, mo);
                sj = sj * __expf(mj - mn) + so * __expf(mo - mn);
                mj = mn;
            }
            if (fg == 0) {
                stM[wave >> 1][wc + j * 16 + cn] = mj;
                stS[wave >> 1][wc + j * 16 + cn] = sj;
            }
        }
        __syncthreads();
        if (tid < 128) {
            float ma = stM[0][tid], mb = stM[1][tid];
            float Mc = fmaxf(ma, mb);
            float Sv = stS[0][tid] * __expf(ma - Mc) + stS[1][tid] * __expf(mb - Mc);
            long o = ((long)z * (M >> 7) + by) * (long)Nc + (long)bx * 128 + tid;
            pmOut[o] = Mc;
            psOut[o] = Sv;
        }
    }
}

// ---------------------------------------------------------------------------
// 256x256 scores GEMM: depth-2 counted-vmcnt global pipeline + XCD-chunked
// mapping + intra-tile ds_read/MFMA interleave.
// C = A @ B^T per batch, triple-product f16 split planes, BK=32,
// 512 threads = 8 waves (2M x 4N), per-wave 128x64.
//
// Round-2 diagnosis: tile time 7104 cyc = serial [read burst 1536][MFMA 1862]
// [read 768][MFMA 1862] — LDS pipe and MFMA pipe take turns because the wave's
// reads and MFMAs are phase-separated. Fix: issue reads in consumption order,
// split MFMA into 3 clusters, let later clusters' reads land under earlier
// clusters' MFMA. Only ~770 cyc (first 8 reads under 8-wave contention) stays
// exposed; ideal tile ~= 770 + 3725 + overhead ~= 4800 cyc.
__global__ __launch_bounds__(512, 2)
void scores_gemm(const f16* __restrict__ Ahi, const f16* __restrict__ Alo,
                 const f16* __restrict__ Bhi, const f16* __restrict__ Blo,
                 float* __restrict__ pmOut, float* __restrict__ psOut,
                 float* __restrict__ C,
                 int M, int Nc, int K, int lda, int ldb, int ldc,
                 long batchA, long batchB, long batchC)
{
    constexpr int PLANE = 256 * GLL_PITCH;   // 8192 f16 = 16 KB

    __shared__ __align__(16) f16 As_hi[2][PLANE];
    __shared__ __align__(16) f16 As_lo[2][PLANE];
    __shared__ __align__(16) f16 Bs_hi[2][PLANE];
    __shared__ __align__(16) f16 Bs_lo[2][PLANE];

    const int tid  = threadIdx.x;
    const int lane = tid & 63;
    const int wave = tid >> 6;
    const int rw   = wave >> 2;      // 0..1 : row half (128 rows)
    const int cw   = wave & 3;       // 0..3 : col quarter (64 cols)
    const int wrM  = rw * 128;
    const int wrN  = cw * 64;
    const int fm   = lane & 15;
    const int fg   = lane >> 4;      // k-chunk index 0..3

    // XCD-chunked remap. Grid is (8,8,4) = 256 blocks, 1/CU; HW round-robins
    // linear id % 8 across XCDs. XCD j gets s=0..31: bx = s&7 (all 8),
    // (by,z) from idx = j*4 + (s>>3) -> 4 pairs, disjoint across XCDs.
    const int Lid = (int)(blockIdx.z * 64 + blockIdx.y * 8 + blockIdx.x);
    const int xcd = Lid & 7;
    const int sct = Lid >> 3;
    const int bxn = sct & 7;
    const int idxp = xcd * 4 + (sct >> 3);
    const int byn = idxp & 7;
    const int zn  = idxp >> 3;

    const int n0 = bxn * 256;
    const int m0 = byn * 256;
    const long z = zn;
    const long aOfs = z * batchA, bOfs = z * batchB, cOfs = z * batchC;

    // staging: 1024 16B slots per 256x32 plane; this thread owns two.
    // slot t holds (row = t>>2, chunk = (t&3) ^ ((row>>1)&3)).
    int slotBase[2], srcA[2], srcB[2];
#pragma unroll
    for (int i = 0; i < 2; i++) {
        int sb = (wave * 2 + i) * 64;        // wave-uniform slot base
        int t  = sb + lane;
        int r  = t >> 2;
        int c  = (t & 3) ^ ((r >> 1) & 3);
        slotBase[i] = sb * 8;                // f16 units
        srcA[i] = (m0 + r) * lda + c * 8;
        srcB[i] = (n0 + r) * ldb + c * 8;
    }

#define SC_STAGE(buf, k0) do {                                              \
    _Pragma("unroll")                                                        \
    for (int s_ = 0; s_ < 2; s_++) {                                         \
        gll16(Ahi + aOfs + srcA[s_] + (k0), &As_hi[buf][slotBase[s_]]);      \
        gll16(Alo + aOfs + srcA[s_] + (k0), &As_lo[buf][slotBase[s_]]);      \
        gll16(Bhi + bOfs + srcB[s_] + (k0), &Bs_hi[buf][slotBase[s_]]);      \
        gll16(Blo + bOfs + srcB[s_] + (k0), &Bs_lo[buf][slotBase[s_]]);      \
    } } while (0)

    f32x4 acc[8][4];
#pragma unroll
    for (int i = 0; i < 8; i++)
#pragma unroll
        for (int j = 0; j < 4; j++) acc[i][j] = (f32x4){0.f, 0.f, 0.f, 0.f};

    int roA[8], roB[4];
#pragma unroll
    for (int i = 0; i < 8; i++) roA[i] = frag_off_gll(wrM + i * 16 + fm, fg);
#pragma unroll
    for (int j = 0; j < 4; j++) roB[j] = frag_off_gll(wrN + j * 16 + fm, fg);

    const int NT = K >> 5;     // 32 K-tiles
    SC_STAGE(0, 0);            // tile 0 -> buf 0   (8 loads)
    SC_STAGE(1, 32);           // tile 1 -> buf 1   (16 loads in flight)

    for (int t = 0; t < NT; t++) {
        const int cur = t & 1;
        // Counted wait: tile t's 8 loads (issued 2 tiles ago) are the oldest
        // 8 of <=16 outstanding. Never drain to 0 in the main loop (T4).
        if (t < NT - 1) {
            asm volatile("s_waitcnt vmcnt(8)" ::: "memory");
        } else {
            asm volatile("s_waitcnt vmcnt(0)" ::: "memory");
        }
        __builtin_amdgcn_sched_barrier(0);
        __builtin_amdgcn_s_barrier();
        __builtin_amdgcn_sched_barrier(0);

        // ---- issue reads in consumption order ----
        // first 8: c1 inputs (Bh, A0h)
        f16x8 bh[4], a0h[4];
#pragma unroll
        for (int j = 0; j < 4; j++) bh[j] = *(const f16x8*)&Bs_hi[cur][roB[j]];
#pragma unroll
        for (int i = 0; i < 4; i++) a0h[i] = *(const f16x8*)&As_hi[cur][roA[i]];
        __builtin_amdgcn_sched_barrier(0);
        // next 8: c2 inputs (Bl, A0l)
        f16x8 bl[4], a0l[4];
#pragma unroll
        for (int j = 0; j < 4; j++) bl[j] = *(const f16x8*)&Bs_lo[cur][roB[j]];
#pragma unroll
        for (int i = 0; i < 4; i++) a0l[i] = *(const f16x8*)&As_lo[cur][roA[i]];
        __builtin_amdgcn_sched_barrier(0);

        // ---- c1: 16 MFMA (a0h x bh); later reads land underneath ----
        __builtin_amdgcn_s_setprio(1);
#pragma unroll
        for (int i = 0; i < 4; i++)
#pragma unroll
            for (int j = 0; j < 4; j++)
                acc[i][j] = __builtin_amdgcn_mfma_f32_16x16x32_f16(a0h[i], bh[j], acc[i][j], 0, 0, 0);
        __builtin_amdgcn_s_setprio(0);
        __builtin_amdgcn_sched_barrier(0);

        // last 8 reads: c3 inputs (A1h, A1l) — issued under c2's MFMA shadow
        f16x8 a1h[4], a1l[4];
#pragma unroll
        for (int i = 0; i < 4; i++) {
            a1h[i] = *(const f16x8*)&As_hi[cur][roA[4 + i]];
            a1l[i] = *(const f16x8*)&As_lo[cur][roA[4 + i]];
        }
        __builtin_amdgcn_sched_barrier(0);

        // ---- c2: 32 MFMA (a0h x bl, a0l x bh) ----
        __builtin_amdgcn_s_setprio(1);
#pragma unroll
        for (int i = 0; i < 4; i++)
#pragma unroll
            for (int j = 0; j < 4; j++)
                acc[i][j] = __builtin_amdgcn_mfma_f32_16x16x32_f16(a0h[i], bl[j], acc[i][j], 0, 0, 0);
#pragma unroll
        for (int i = 0; i < 4; i++)
#pragma unroll
            for (int j = 0; j < 4; j++)
                acc[i][j] = __builtin_amdgcn_mfma_f32_16x16x32_f16(a0l[i], bh[j], acc[i][j], 0, 0, 0);
        __builtin_amdgcn_s_setprio(0);

        // all ds_reads from buf cur complete -> safe to restage after barrier
        asm volatile("s_waitcnt lgkmcnt(0)" ::: "memory");
        __builtin_amdgcn_sched_barrier(0);
        __builtin_amdgcn_s_barrier();     // all waves done reading buf cur
        __builtin_amdgcn_sched_barrier(0);

        if (t + 2 < NT) SC_STAGE(cur, (t + 2) * 32);   // refill buf cur

        // ---- c3: 48 MFMA (a1h x bh, a1h x bl, a1l x bh), overlaps stage ----
        __builtin_amdgcn_s_setprio(1);
#pragma unroll
        for (int i = 0; i < 4; i++)
#pragma unroll
            for (int j = 0; j < 4; j++)
                acc[4 + i][j] = __builtin_amdgcn_mfma_f32_16x16x32_f16(a1h[i], bh[j], acc[4 + i][j], 0, 0, 0);
#pragma unroll
        for (int i = 0; i < 4; i++)
#pragma unroll
            for (int j = 0; j < 4; j++)
                acc[4 + i][j] = __builtin_amdgcn_mfma_f32_16x16x32_f16(a1h[i], bl[j], acc[4 + i][j], 0, 0, 0);
#pragma unroll
        for (int i = 0; i < 4; i++)
#pragma unroll
            for (int j = 0; j < 4; j++)
                acc[4 + i][j] = __builtin_amdgcn_mfma_f32_16x16x32_f16(a1l[i], bh[j], acc[4 + i][j], 0, 0, 0);
        __builtin_amdgcn_s_setprio(0);
    }
#undef SC_STAGE

    // Epilogue: f32 C write. C/D frag: col = lane&15, row = (lane>>4)*4 + reg.
    const int cr = fg * 4;
#pragma unroll
    for (int i = 0; i < 8; i++) {
#pragma unroll
        for (int j = 0; j < 4; j++) {
#pragma unroll
            for (int r = 0; r < 4; r++) {
                long mg = m0 + wrM + i * 16 + cr + r;
                long ng = n0 + wrN + j * 16 + fm;
                C[cOfs + mg * (long)ldc + ng] = acc[i][j][r];
            }
        }
    }

    // Fused column-softmax partials over this tile's 256 q-rows.
    __shared__ float stM[2][256];
    __shared__ float stS[2][256];
#pragma unroll
    for (int j = 0; j < 4; j++) {
        float mj = -3.402823466e38f;
#pragma unroll
        for (int i = 0; i < 8; i++)
#pragma unroll
            for (int r = 0; r < 4; r++) mj = fmaxf(mj, acc[i][j][r]);
        float sj = 0.f;
#pragma unroll
        for (int i = 0; i < 8; i++)
#pragma unroll
            for (int r = 0; r < 4; r++) sj += __expf(acc[i][j][r] - mj);
#pragma unroll
        for (int mask = 16; mask <= 32; mask <<= 1) {
            float mo = __shfl_xor(mj, mask, 64);
            float so = __shfl_xor(sj, mask, 64);
            float mn = fmaxf(mj, mo);
            sj = sj * __expf(mj - mn) + so * __expf(mo - mn);
            mj = mn;
        }
        if (fg == 0) {
            stM[rw][wrN + j * 16 + fm] = mj;
            stS[rw][wrN + j * 16 + fm] = sj;
        }
    }
    __syncthreads();
    if (tid < 256) {
        float ma = stM[0][tid], mb = stM[1][tid];
        float Mc = fmaxf(ma, mb);
        float Sv = stS[0][tid] * __expf(ma - Mc) + stS[1][tid] * __expf(mb - Mc);
        long o = ((long)z * (M >> 8) + byn) * (long)Nc + (long)bxn * 256 + tid;
        pmOut[o] = Mc;
        psOut[o] = Sv;
    }
}

// Elementwise f32 -> f16 hi (+ optional lo) split. n multiple of 2048.
template<bool HAS_LO>
__global__ __launch_bounds__(256)
void split_kernel(const float* __restrict__ src, f16* __restrict__ hi,
                  f16* __restrict__ lo, long n)
{
    long i = ((long)blockIdx.x * 256 + threadIdx.x) * 8;
    if (i >= n) return;
    float4 x0 = *(const float4*)&src[i];
    float4 x1 = *(const float4*)&src[i + 4];
    float xs[8] = {x0.x, x0.y, x0.z, x0.w, x1.x, x1.y, x1.z, x1.w};
    f16x8 h, l;
#pragma unroll
    for (int e = 0; e < 8; e++) {
        f16 hh = (f16)xs[e];
        h[e] = hh;
        if (HAS_LO) l[e] = (f16)(xs[e] - (float)hh);
    }
    *(f16x8*)&hi[i] = h;
    if (HAS_LO) *(f16x8*)&lo[i] = l;
}

// Fold the CH q-chunk partials -> m[k], r[k] = 1/sum.
template<int CH>
__global__ __launch_bounds__(64)
void stats_combine_kernel(const float* __restrict__ pm, const float* __restrict__ ps,
                          float* __restrict__ statM, float* __restrict__ statR, int S)
{
    const int n = blockIdx.y;
    const int kk = blockIdx.x * 64 + threadIdx.x;
    float M = -INFINITY;
#pragma unroll
    for (int i = 0; i < CH; i++)
        M = fmaxf(M, pm[((long)n * CH + i) * S + kk]);
    float Ssum = 0.f;
#pragma unroll
    for (int i = 0; i < CH; i++)
        Ssum += ps[((long)n * CH + i) * S + kk] * __expf(pm[((long)n * CH + i) * S + kk] - M);
    statM[(long)n * S + kk] = M;
    statR[(long)n * S + kk] = 1.0f / Ssum;
}

// P_hi = (f16)(exp(Sc - m[k]) * r[k]).  Grid: (S/1024, S/32, N); thread = 4 k cols.
__global__ __launch_bounds__(256)
void pmat_kernel(const float* __restrict__ Sc, const float* __restrict__ statM,
                 const float* __restrict__ statR, f16* __restrict__ Phi, int S)
{
    const int n = blockIdx.z;
    const int kk = blockIdx.x * 1024 + threadIdx.x * 4;
    const float* Sn = Sc + (long)n * S * S;
    f16* ph = Phi + (long)n * S * S;
    float4 M4 = *(const float4*)&statM[(long)n * S + kk];
    float4 R4 = *(const float4*)&statR[(long)n * S + kk];
    const int q0 = blockIdx.y * 32;
    for (int qi = 0; qi < 32; qi++) {
        long idx = (long)(q0 + qi) * S + kk;
        float4 x = *(const float4*)&Sn[idx];
        f16x4 p;
        p[0] = (f16)(__expf(x.x - M4.x) * R4.x);
        p[1] = (f16)(__expf(x.y - M4.y) * R4.y);
        p[2] = (f16)(__expf(x.z - M4.z) * R4.z);
        p[3] = (f16)(__expf(x.w - M4.w) * R4.w);
        *(f16x4*)&ph[idx] = p;
    }
}

extern "C" void kernel_launch(void* const* d_in, const int* in_sizes, int n_in,
                              void* d_out, int out_size, void* d_ws, size_t ws_size,
                              hipStream_t stream)
{
    const float* v  = (const float*)d_in[0];
    const float* k  = (const float*)d_in[1];
    const float* q  = (const float*)d_in[2];
    const float* WV = (const float*)d_in[3];
    const float* WQ = (const float*)d_in[4];
    const float* WK = (const float*)d_in[5];
    float* out = (float*)d_out;

    const int N = 4, S = 2048, D = 1024;
    const long NSD = (long)N * S * D;   // 8388608
    const long DD  = (long)D * D;       // 1048576

    f16* ws = (f16*)d_ws;
    // phase-1 buffers
    f16* q_hi = ws;                 // [0,1)N
    f16* q_lo = ws + NSD;           // [1,2)N
    f16* k_hi = ws + 2 * NSD;
    f16* k_lo = ws + 3 * NSD;
    f16* v_hi = ws + 4 * NSD;
    f16* Wb   = ws + 5 * NSD;       // weight planes
    f16* WQ_hi = Wb,          *WQ_lo = Wb + DD;
    f16* WK_hi = Wb + 2 * DD, *WK_lo = Wb + 3 * DD;
    f16* WV_hi = Wb + 4 * DD;
    // projection outputs
    f16* wq_hi = ws + 5 * NSD + 5 * DD;
    f16* wq_lo = wq_hi + NSD;
    f16* wk_hi = wq_hi + 2 * NSD;
    f16* wk_lo = wq_hi + 3 * NSD;
    // aliases (lifetime-checked):
    f16* wvT_hi = ws;                       // [0,1)N — q_hi dead after q-proj
    float* Sc   = (float*)(ws + NSD);       // [1,5)N — q_lo/k/v dead by scores
    f16* P_hi   = wq_hi;                    // wq/wk dead after scores
    // stats: pm/ps are [N][8][S] (256^2 scores tile => 8 q-chunks)
    float* pm    = (float*)(ws + 9 * NSD + 5 * DD);
    float* ps    = pm + (long)N * 8 * S;
    float* statM = ps + (long)N * 8 * S;
    float* statR = statM + (long)N * S;

    dim3 blk(256);

    // ---- split pre-pass ----
    split_kernel<true ><<<dim3(NSD / 2048), blk, 0, stream>>>(q,  q_hi, q_lo, NSD);
    split_kernel<true ><<<dim3(NSD / 2048), blk, 0, stream>>>(k,  k_hi, k_lo, NSD);
    split_kernel<false><<<dim3(NSD / 2048), blk, 0, stream>>>(v,  v_hi, nullptr, NSD);
    split_kernel<true ><<<dim3(DD / 2048),  blk, 0, stream>>>(WQ, WQ_hi, WQ_lo, DD);
    split_kernel<true ><<<dim3(DD / 2048),  blk, 0, stream>>>(WK, WK_hi, WK_lo, DD);
    split_kernel<false><<<dim3(DD / 2048),  blk, 0, stream>>>(WV, WV_hi, nullptr, DD);

    // ---- projections: M = N*S folded, C = X @ W^T ----
    {
        dim3 g(D / 128, (N * S) / 128, 1);
        mfma_gemm<SM_PLANES2, SM_PLANES2, EPI_SPLIT, 4, false><<<g, blk, 0, stream>>>(
            q_hi, q_lo, WQ_hi, WQ_lo, nullptr, nullptr, wq_hi, wq_lo,
            N * S, D, D, D, D, D, 0, 0, 0, 1.0f, 0);
        mfma_gemm<SM_PLANES2, SM_PLANES2, EPI_SPLIT, 4, false><<<g, blk, 0, stream>>>(
            k_hi, k_lo, WK_hi, WK_lo, nullptr, nullptr, wk_hi, wk_lo,
            N * S, D, D, D, D, D, 0, 0, 0, 1.0f, 0);
        mfma_gemm<SM_PLANES1, SM_PLANES1, EPI_F16T, 4, false><<<g, blk, 0, stream>>>(
            v_hi, nullptr, WV_hi, nullptr, nullptr, nullptr, wvT_hi, nullptr,
            N * S, D, D, D, D, 0, 0, 0, 0, 1.0f, 11 /* tsShift: S=2048 */);
    }
    // ---- scores: Sc[n] = wq[n] @ wk[n]^T (f32) + fused column-stat partials ----
    // 256^2 counted-vmcnt kernel: grid (8,8,4) = 256 blocks = 1/CU, XCD-chunked.
    {
        dim3 g(S / 256, S / 256, N);
        scores_gemm<<<g, dim3(512), 0, stream>>>(
            wq_hi, wq_lo, wk_hi, wk_lo, pm, ps, Sc,
            S, S, D, D, D, S, (long)S * D, (long)S * D, (long)S * S);
    }
    // ---- combine partials -> statM, statR ----
    {
        dim3 gB(S / 64, N);
        stats_combine_kernel<8><<<gB, dim3(64), 0, stream>>>(pm, ps, statM, statR, S);
    }
    // ---- P_hi = exp(Sc - m)*r ----
    {
        dim3 g(S / 1024, S / 32, N);
        pmat_kernel<<<g, blk, 0, stream>>>(Sc, statM, statR, P_hi, S);
    }
    // ---- out[n] = (P[n] @ wvT[n]^T) / 1024 ----
    {
        dim3 g(D / 128, S / 128, N);
        mfma_gemm<SM_PLANES1, SM_PLANES1, EPI_F32, 4, false><<<g, blk, 0, stream>>>(
            P_hi, nullptr, wvT_hi, nullptr, nullptr, nullptr, out, nullptr,
            S, D, S, S, S, D, (long)S * S, (long)S * D, (long)S * D, 1.0f / (float)D, 0);
    }
}